// Round 16
// baseline (162.629 us; speedup 1.0000x reference)
//
#include <hip/hip_runtime.h>

#define NTOT 1536
#define DD 2048
#define BB 4
#define SS 4096
#define NBB 42          // partial blocks per (group,b)
#define TPB 98          // ceil(4096/42)
#define NTILE 7         // 7*16 = 112 >= 98 token slots per block

typedef __attribute__((ext_vector_type(8))) short bf16x8;
typedef __attribute__((ext_vector_type(4))) float f32x4;

__device__ __forceinline__ void split1(float v, unsigned short& hi, unsigned short& lo) {
  unsigned u = __float_as_uint(v);
  hi = (unsigned short)(u >> 16);
  float hf = __uint_as_float(u & 0xffff0000u);
  float r = v - hf;
  lo = (unsigned short)(__float_as_uint(r) >> 16);
}

// async 16B global->LDS (no VGPR round-trip); LDS dest = wave base + lane*16,
// global src is per-lane (pre-swizzled where needed, m173 pattern)
__device__ __forceinline__ void gload16(const void* g, void* lds) {
  __builtin_amdgcn_global_load_lds(
      (const __attribute__((address_space(1))) unsigned int*)g,
      (__attribute__((address_space(3))) unsigned int*)lds, 16, 0, 0);
}

// ---------------- kernel 1: h = x @ W + b via hi/lo bf16 MFMA -----------------
// W-prep INLINED (k_prep node removed): per tile each thread loads 16 W fp32
// (L2-resident, 512 KB total), splits hi/lo in regs, ds_writes into the
// swizzled BHs/BLs layout at linear ci*16B chunks (conflict-free). The extra
// VALU hides under the x-read HBM stall (proj sits at the 21.3 us floor).
__global__ __launch_bounds__(256, 2) void k_proj(const float* __restrict__ x,
                                                 const float* __restrict__ W,
                                                 const float* __restrict__ bias,
                                                 short* __restrict__ hH,
                                                 short* __restrict__ hL) {
  __shared__ float XAs[2][2048];   // [tok 0..31][64 k]; phys slot p holds logical p^(tok&7)
  __shared__ short BHs[2][4096];   // [n][p*8] swizzled: p holds logical p^(n&7)
  __shared__ short BLs[2][4096];

  int tid = threadIdx.x;           // 0..255
  int w = tid >> 6;                // 0..3
  int l = tid & 63;
  size_t t0 = (size_t)blockIdx.x * 32;

  int th = (w & 1) * 16;           // token half
  int nh = (w >> 1) * 32;          // n half

  f32x4 acc[2];
#pragma unroll
  for (int i = 0; i < 2; ++i) acc[i] = (f32x4){0.f, 0.f, 0.f, 0.f};

  // x staging geometry (gload_lds, linear dest / pre-swizzled src)
  size_t xoff[2];
  int xdst[2];
#pragma unroll
  for (int c = 0; c < 2; ++c) {
    int tok = c * 16 + w * 4 + (l >> 4);
    int s = (l & 15) ^ (tok & 7);
    xoff[c] = (t0 + tok) * DD + s * 4;
    xdst[c] = tok * 64 + (l & 15) * 4;
  }

  // W chunk geometry: chunk ci = c*256+tid -> (n=ci>>3, p=ci&7); LDS short-idx ci*8
  int wn[2], wp[2], wdst[2];
#pragma unroll
  for (int c = 0; c < 2; ++c) {
    int ci = c * 256 + tid;
    wn[c] = ci >> 3;
    wp[c] = ci & 7;
    wdst[c] = ci * 8;
  }
  float wreg[2][8];

#define STAGE_X(DB, KT)                                                      \
  {                                                                          \
    gload16(x + xoff[0] + (KT) * 64, &XAs[DB][xdst[0]]);                     \
    gload16(x + xoff[1] + (KT) * 64, &XAs[DB][xdst[1]]);                     \
  }

#define LOADW(KT)                                                            \
  {                                                                          \
    _Pragma("unroll") for (int c = 0; c < 2; ++c) {                          \
      int kb = (KT) * 64 + ((wp[c] ^ (wn[c] & 7)) * 8);                      \
      _Pragma("unroll") for (int e = 0; e < 8; ++e)                          \
        wreg[c][e] = W[(size_t)(kb + e) * 64 + wn[c]];                       \
    }                                                                        \
  }

#define WRITE_W(DB)                                                          \
  {                                                                          \
    _Pragma("unroll") for (int c = 0; c < 2; ++c) {                          \
      bf16x8 hi8, lo8;                                                       \
      _Pragma("unroll") for (int e = 0; e < 8; ++e) {                        \
        unsigned short hh, ll;                                               \
        split1(wreg[c][e], hh, ll);                                          \
        hi8[e] = (short)hh;                                                  \
        lo8[e] = (short)ll;                                                  \
      }                                                                      \
      *(bf16x8*)(&BHs[DB][wdst[c]]) = hi8;                                   \
      *(bf16x8*)(&BLs[DB][wdst[c]]) = lo8;                                   \
    }                                                                        \
  }

#define COMPUTE(DB)                                                                \
  {                                                                                \
    int row = th + (l & 15);                                                       \
    _Pragma("unroll") for (int ks = 0; ks < 2; ++ks) {                             \
      int s0 = ks * 8 + (l >> 4) * 2;                                              \
      float4 xa = *(const float4*)(&XAs[DB][row * 64 + ((s0 ^ (row & 7)) << 2)]);  \
      float4 xb = *(const float4*)(&XAs[DB][row * 64 + (((s0 + 1) ^ (row & 7)) << 2)]); \
      bf16x8 ahi, alo;                                                             \
      {                                                                            \
        float v[8] = {xa.x, xa.y, xa.z, xa.w, xb.x, xb.y, xb.z, xb.w};             \
        _Pragma("unroll") for (int i = 0; i < 8; ++i) {                            \
          unsigned u = __float_as_uint(v[i]);                                      \
          ahi[i] = (short)(u >> 16);                                               \
          float hf = __uint_as_float(u & 0xffff0000u);                             \
          float r = v[i] - hf;                                                     \
          alo[i] = (short)(__float_as_uint(r) >> 16);                              \
        }                                                                          \
      }                                                                            \
      _Pragma("unroll") for (int nf = 0; nf < 2; ++nf) {                           \
        int n = nh + nf * 16 + (l & 15);                                           \
        int p = (ks * 4 + (l >> 4)) ^ (n & 7);                                     \
        bf16x8 bh = *(const bf16x8*)(&BHs[DB][n * 64 + p * 8]);                    \
        bf16x8 bl = *(const bf16x8*)(&BLs[DB][n * 64 + p * 8]);                    \
        acc[nf] = __builtin_amdgcn_mfma_f32_16x16x32_bf16(ahi, bh, acc[nf], 0, 0, 0); \
        acc[nf] = __builtin_amdgcn_mfma_f32_16x16x32_bf16(alo, bh, acc[nf], 0, 0, 0); \
        acc[nf] = __builtin_amdgcn_mfma_f32_16x16x32_bf16(ahi, bl, acc[nf], 0, 0, 0); \
      }                                                                            \
    }                                                                              \
  }

  // prologue: tile 0
  STAGE_X(0, 0);
  LOADW(0);
  WRITE_W(0);
  __syncthreads();

  int db = 0;
#pragma unroll 1
  for (int kt = 0; kt < 32; ++kt) {
    if (kt < 31) {
      STAGE_X(db ^ 1, kt + 1);    // async x loads fly under COMPUTE
      LOADW(kt + 1);              // W loads (L2) overlap COMPUTE too
    }
    COMPUTE(db);
    if (kt < 31) WRITE_W(db ^ 1); // split + ds_write before barrier
    __syncthreads();
    db ^= 1;
  }

  // epilogue: token = t0 + th + (l>>4)*4+j, n = nh + nf*16 + (l&15)
#pragma unroll
  for (int nf = 0; nf < 2; ++nf) {
    int n = nh + nf * 16 + (l & 15);
    float bv = bias[n];
#pragma unroll
    for (int j = 0; j < 4; ++j) {
      size_t tok = t0 + th + (l >> 4) * 4 + j;
      float v = acc[nf][j] + bv;
      unsigned short hi, lo;
      split1(v, hi, lo);
      hH[tok * 64 + n] = (short)hi;
      hL[tok * 64 + n] = (short)lo;
    }
  }
#undef STAGE_X
#undef LOADW
#undef WRITE_W
#undef COMPUTE
}

// ---------------- kernel 2: MFMA logits -> softmax -> importance pooling ----------
// emb normalize+split INLINED (same bytes read as the old eH/eL: 256 B/thread);
// row-ssq via local sum + shfl_xor over the q-lane groups (lanes l^16, l^32).
__global__ __launch_bounds__(512, 4) void k_pref(const short* __restrict__ hH,
                                                 const short* __restrict__ hL,
                                                 const float* __restrict__ emb,
                                                 const float* __restrict__ imp,
                                                 float* __restrict__ partials) {
  int bid = blockIdx.x;
  int g = bid / (BB * NBB);
  int rem = bid % (BB * NBB);
  int b = rem / NBB;
  int nb = rem % NBB;
  int tid = threadIdx.x;
  int w = tid >> 6;
  int l = tid & 63;
  int col = l & 15;
  int q = l >> 4;

  __shared__ short BLs[4 * 2 * 512 * 8];   // 65536 B: [nf][ks][tid] 16B slots
  __shared__ float zred[2][8][16];

  // B-fragments: neuron n = g*512 + w*64 + nf*16 + col; k = ks*32 + q*8 + e
  bf16x8 BH[4][2];
  {
    const float* eg = emb + ((size_t)(g * 512 + w * 64 + col)) * 64 + q * 8;
#pragma unroll
    for (int nf = 0; nf < 4; ++nf) {
      float4 a0 = *(const float4*)(eg + nf * 1024);        // ks=0, e 0..3
      float4 a1 = *(const float4*)(eg + nf * 1024 + 4);    // ks=0, e 4..7
      float4 b0 = *(const float4*)(eg + nf * 1024 + 32);   // ks=1, e 0..3
      float4 b1 = *(const float4*)(eg + nf * 1024 + 36);   // ks=1, e 4..7
      float ss = a0.x * a0.x + a0.y * a0.y + a0.z * a0.z + a0.w * a0.w +
                 a1.x * a1.x + a1.y * a1.y + a1.z * a1.z + a1.w * a1.w +
                 b0.x * b0.x + b0.y * b0.y + b0.z * b0.z + b0.w * b0.w +
                 b1.x * b1.x + b1.y * b1.y + b1.z * b1.z + b1.w * b1.w;
      ss += __shfl_xor(ss, 16, 64);     // sum over the 4 q-groups holding this row
      ss += __shfl_xor(ss, 32, 64);
      float nrm = fmaxf(sqrtf(ss), 1e-12f);
      float inv = 1.0f / nrm;
      float va[8] = {a0.x, a0.y, a0.z, a0.w, a1.x, a1.y, a1.z, a1.w};
      float vb[8] = {b0.x, b0.y, b0.z, b0.w, b1.x, b1.y, b1.z, b1.w};
      bf16x8 h0, l0, h1, l1;
#pragma unroll
      for (int e = 0; e < 8; ++e) {
        unsigned short hh, ll;
        split1(va[e] * inv, hh, ll);
        h0[e] = (short)hh; l0[e] = (short)ll;
        split1(vb[e] * inv, hh, ll);
        h1[e] = (short)hh; l1[e] = (short)ll;
      }
      BH[nf][0] = h0;
      BH[nf][1] = h1;
      *(bf16x8*)(&BLs[((nf * 2 + 0) * 512 + tid) * 8]) = l0;
      *(bf16x8*)(&BLs[((nf * 2 + 1) * 512 + tid) * 8]) = l1;
    }
  }
  __syncthreads();

  int s0 = nb * TPB;
  int slim = s0 + TPB; if (slim > SS) slim = SS;
  float wsum[4] = {0.f, 0.f, 0.f, 0.f};
  int par = 0;

#pragma unroll 1
  for (int tile = 0; tile < NTILE; ++tile) {
    int tbase = s0 + tile * 16;
    int arow = tbase + col; if (arow > SS - 1) arow = SS - 1;
    size_t hoff = ((size_t)b * SS + arow) * 64;
    bf16x8 AH0 = *(const bf16x8*)(hH + hoff + q * 8);
    bf16x8 AH1 = *(const bf16x8*)(hH + hoff + 32 + q * 8);
    bf16x8 AL0 = *(const bf16x8*)(hL + hoff + q * 8);
    bf16x8 AL1 = *(const bf16x8*)(hL + hoff + 32 + q * 8);

    f32x4 acc[4];
#pragma unroll
    for (int nf = 0; nf < 4; ++nf) acc[nf] = (f32x4){0.f, 0.f, 0.f, 0.f};
#pragma unroll
    for (int nf = 0; nf < 4; ++nf) {
      bf16x8 bl0 = *(const bf16x8*)(&BLs[((nf * 2 + 0) * 512 + tid) * 8]);
      bf16x8 bl1 = *(const bf16x8*)(&BLs[((nf * 2 + 1) * 512 + tid) * 8]);
      acc[nf] = __builtin_amdgcn_mfma_f32_16x16x32_bf16(AH0, BH[nf][0], acc[nf], 0, 0, 0);
      acc[nf] = __builtin_amdgcn_mfma_f32_16x16x32_bf16(AL0, BH[nf][0], acc[nf], 0, 0, 0);
      acc[nf] = __builtin_amdgcn_mfma_f32_16x16x32_bf16(AH0, bl0, acc[nf], 0, 0, 0);
      acc[nf] = __builtin_amdgcn_mfma_f32_16x16x32_bf16(AH1, BH[nf][1], acc[nf], 0, 0, 0);
      acc[nf] = __builtin_amdgcn_mfma_f32_16x16x32_bf16(AL1, BH[nf][1], acc[nf], 0, 0, 0);
      acc[nf] = __builtin_amdgcn_mfma_f32_16x16x32_bf16(AH1, bl1, acc[nf], 0, 0, 0);
    }

    // e[] kept live (VGPR ~80 < 128 cap): halves the v_exp count vs recompute
    float e0[4], e1[4], e2[4], e3[4], zp[4];
#pragma unroll
    for (int j = 0; j < 4; ++j) {
      e0[j] = __expf(acc[0][j]);
      e1[j] = __expf(acc[1][j]);
      e2[j] = __expf(acc[2][j]);
      e3[j] = __expf(acc[3][j]);
      zp[j] = e0[j] + e1[j] + e2[j] + e3[j];
    }
#pragma unroll
    for (int off = 1; off <= 8; off <<= 1) {
#pragma unroll
      for (int j = 0; j < 4; ++j) zp[j] += __shfl_xor(zp[j], off, 64);
    }
    float zw = (col == 0) ? zp[0] : (col == 1) ? zp[1] : (col == 2) ? zp[2] : zp[3];
    if (col < 4) zred[par][w][q * 4 + col] = zw;
    __syncthreads();
    float r0, r1, r2, r3;
#pragma unroll
    for (int j = 0; j < 4; ++j) {
      int t16 = q * 4 + j;
      float Z = 0.f;
#pragma unroll
      for (int ww = 0; ww < 8; ++ww) Z += zred[par][ww][t16];
      int s = tbase + t16;
      float iv = (s < slim) ? imp[(size_t)b * SS + s] : 0.f;
      float r = iv / Z;
      if (j == 0) r0 = r; else if (j == 1) r1 = r; else if (j == 2) r2 = r; else r3 = r;
    }
    wsum[0] += e0[0] * r0 + e0[1] * r1 + e0[2] * r2 + e0[3] * r3;
    wsum[1] += e1[0] * r0 + e1[1] * r1 + e1[2] * r2 + e1[3] * r3;
    wsum[2] += e2[0] * r0 + e2[1] * r1 + e2[2] * r2 + e2[3] * r3;
    wsum[3] += e3[0] * r0 + e3[1] * r1 + e3[2] * r2 + e3[3] * r3;
    par ^= 1;
  }

#pragma unroll
  for (int nf = 0; nf < 4; ++nf) {
    wsum[nf] += __shfl_xor(wsum[nf], 16, 64);
    wsum[nf] += __shfl_xor(wsum[nf], 32, 64);
  }
  if (q == 0) {
    size_t base = ((size_t)(g * BB + b) * NBB + nb) * 512 + w * 64;
#pragma unroll
    for (int nf = 0; nf < 4; ++nf) partials[base + nf * 16 + col] = wsum[nf];
  }
}

// ---------------- kernel 3: reduce partials + top-k + renormalize ----------------
__global__ __launch_bounds__(512) void k_topk(const float* __restrict__ partials,
                                              float* __restrict__ out) {
  int g = blockIdx.x >> 2;   // 0..2
  int b = blockIdx.x & 3;
  int tid = threadIdx.x;     // neuron 0..511
  int wave = tid >> 6, lane = tid & 63;

  __shared__ float lv[8];
  __shared__ int li[8];

  // 4-way ILP partial sum
  float d0 = 0.f, d1 = 0.f, d2 = 0.f, d3 = 0.f;
  const float* p = partials + (size_t)(g * BB + b) * NBB * 512 + tid;
  int nb = 0;
  for (; nb + 4 <= NBB; nb += 4) {
    d0 += p[(nb + 0) * 512];
    d1 += p[(nb + 1) * 512];
    d2 += p[(nb + 2) * 512];
    d3 += p[(nb + 3) * 512];
  }
  for (; nb < NBB; ++nb) d0 += p[nb * 512];
  float dense = (d0 + d1) + (d2 + d3);

  int K = (g == 0) ? 8 : (g == 1) ? 4 : 6;
  float val = dense;
  float ssum = 0.f;
  int sel = 0;
  for (int it = 0; it < K; ++it) {
    float v = val;
    int idx = tid;
#pragma unroll
    for (int off = 32; off; off >>= 1) {
      float ov = __shfl_xor(v, off, 64);
      int oi = __shfl_xor(idx, off, 64);
      if (ov > v || (ov == v && oi < idx)) { v = ov; idx = oi; }
    }
    if (lane == 0) { lv[wave] = v; li[wave] = idx; }
    __syncthreads();
    float mv = lv[0];
    int mi = li[0];
#pragma unroll
    for (int ww = 1; ww < 8; ++ww) {
      float wv2 = lv[ww];
      int wi = li[ww];
      if (wv2 > mv || (wv2 == mv && wi < mi)) { mv = wv2; mi = wi; }
    }
    ssum += mv;
    if (tid == mi) { sel = 1; val = -3.0e38f; }
    __syncthreads();
  }
  float o = sel ? dense / (ssum + 1e-8f) : 0.f;
  int row = (g == 0) ? 0 : (g == 1) ? 1 : 3;
  out[((size_t)row * BB + b) * 512 + tid] = o;
  if (g == 1) out[((size_t)2 * BB + b) * 512 + tid] = o;
}

extern "C" void kernel_launch(void* const* d_in, const int* in_sizes, int n_in,
                              void* d_out, int out_size, void* d_ws, size_t ws_size,
                              hipStream_t stream) {
  const float* x    = (const float*)d_in[0];
  const float* imp  = (const float*)d_in[1];
  const float* W    = (const float*)d_in[2];
  const float* bias = (const float*)d_in[3];
  const float* emb  = (const float*)d_in[4];
  float* out = (float*)d_out;

  char* ws = (char*)d_ws;
  short* hH       = (short*)(ws + 0);          // 2097152 B
  short* hL       = (short*)(ws + 2097152);    // 2097152 B
  float* partials = (float*)(ws + 4194304);    // 12*42*512*4 = 1032192 B

  hipLaunchKernelGGL(k_proj, dim3(512), dim3(256), 0, stream, x, W, bias, hH, hL);
  hipLaunchKernelGGL(k_pref, dim3(3 * BB * NBB), dim3(512), 0, stream,
                     hH, hL, emb, imp, partials);
  hipLaunchKernelGGL(k_topk, dim3(12), dim3(512), 0, stream, partials, out);
}